// Round 12
// baseline (419.046 us; speedup 1.0000x reference)
//
#include <hip/hip_runtime.h>
#include <hip/hip_bf16.h>

#define NNODES 50000
#define DIM 128
#define NREL 3
#define NEDGE 800000
#define NBKT 196             // ceil(NNODES/256) coarse buckets (dst>>8)
#define CH 391               // ceil(NEDGE/2048) edge chunks
// K of the fused GEMM = DIM (self) + NREL*DIM (means) = 512

typedef __attribute__((ext_vector_type(8))) short bf16x8;     // 8 bf16 in 4 VGPRs
typedef __attribute__((ext_vector_type(4))) float f32x4;      // MFMA accumulator
typedef __attribute__((ext_vector_type(8))) unsigned short ushortx8;

__device__ __forceinline__ ushort f2bf(float x) {             // RNE fp32->bf16
    unsigned u = __float_as_uint(x);
    return (ushort)((u + 0x7fffu + ((u >> 16) & 1u)) >> 16);
}
__device__ __forceinline__ float bf2f(ushort h) {
    return __uint_as_float(((unsigned)h) << 16);
}

// ---------------------------------------------------------------------------
// 0. S[l] = sum_r Wm_r[l]  (128x128 per layer) — hoisted out of prep_wsplit
// ---------------------------------------------------------------------------
__global__ void sumS(const float* __restrict__ Wm, float* __restrict__ S) {
    const int l = blockIdx.y, k = blockIdx.x, j = threadIdx.x;
    const float* Wm_l = Wm + (size_t)l * 3 * DIM * DIM;
    S[((size_t)l * DIM + k) * DIM + j] =
        Wm_l[k * DIM + j] + Wm_l[(DIM + k) * DIM + j] + Wm_l[(2 * DIM + k) * DIM + j];
}

// ---------------------------------------------------------------------------
// 1. Fold weights AND split hi/lo bf16 in MFMA B-fragment order (fused):
//    Wf[l](512x128) = [ W_self@S ; W_neigh@Wm_0 ; W_neigh@Wm_1 ; W_neigh@Wm_2 ],
//    bias c[l] = b_self@S + bm.
//    frag off = (((kt*8+ct)*4+kg)*16+col)*8 + e — matches gemm_mfma B-frag reads.
// ---------------------------------------------------------------------------
__global__ void prep_wsplit(const float* __restrict__ Wself, const float* __restrict__ bself,
                            const float* __restrict__ Wneigh, const float* __restrict__ Wm,
                            const float* __restrict__ bm, const float* __restrict__ S,
                            ushort* __restrict__ Whi, ushort* __restrict__ Wlo,
                            float* __restrict__ bias) {
    const int l = blockIdx.y;
    const int i = blockIdx.x;          // 0..512 (512 => bias row)
    const int j = threadIdx.x;         // 0..127
    const float* S_l = S + (size_t)l * DIM * DIM;
    if (i == 512) {
        float acc = bm[l * DIM + j];
        for (int k = 0; k < DIM; ++k) acc += bself[l * DIM + k] * S_l[k * DIM + j];
        bias[l * DIM + j] = acc;
        return;
    }
    float acc = 0.f;
    if (i < DIM) {                     // W_self @ S
        const float* A = Wself + (size_t)l * DIM * DIM + (size_t)i * DIM;
        for (int k = 0; k < DIM; ++k) acc += A[k] * S_l[k * DIM + j];
    } else {                           // W_neigh @ Wm_r  (row a of block r)
        const int r = (i - DIM) >> 7;
        const int a = (i - DIM) & 127;
        const float* A = Wneigh + (size_t)l * DIM * DIM + (size_t)a * DIM;
        const float* B = Wm + (size_t)l * 3 * DIM * DIM + (size_t)r * DIM * DIM;
        for (int k = 0; k < DIM; ++k) acc += A[k] * B[k * DIM + j];
    }
    const ushort h  = f2bf(acc);
    const ushort lo = f2bf(acc - bf2f(h));
    const int kt = i >> 5, kl = i & 31, kg = kl >> 3, e = kl & 7;
    const int ct = j >> 4, col = j & 15;
    const size_t off = (size_t)l * 65536 + ((((kt * 8 + ct) * 4 + kg) * 16 + col) * 8 + e);
    Whi[off] = h;
    Wlo[off] = lo;
}

// ---------------------------------------------------------------------------
// 1c. fp32 -> bf16 table conversion (coalesced; only needed for feats)
// ---------------------------------------------------------------------------
__global__ __launch_bounds__(256) void h2bf(const float* __restrict__ in,
                                            ushort* __restrict__ out) {
    const int i = (blockIdx.x * 256 + threadIdx.x) * 4;   // NNODES*DIM/4 threads
    if (i >= NNODES * DIM) return;
    const float4 v = *reinterpret_cast<const float4*>(in + i);
    ushort4 o;
    o.x = f2bf(v.x); o.y = f2bf(v.y); o.z = f2bf(v.z); o.w = f2bf(v.w);
    *reinterpret_cast<ushort4*>(out + i) = o;
}

// ---------------------------------------------------------------------------
// 2. Zero-global-atomic CSR build: two-level counting sort by dst.
// ---------------------------------------------------------------------------
__global__ __launch_bounds__(256) void hist_bkt(const int* __restrict__ dst,
                                                int* __restrict__ hist) {
    const int c = blockIdx.x, r = blockIdx.y;
    __shared__ int h[NBKT];
    for (int t = threadIdx.x; t < NBKT; t += 256) h[t] = 0;
    __syncthreads();
    #pragma unroll
    for (int u = 0; u < 8; ++u) {
        const int e = c * 2048 + u * 256 + threadIdx.x;
        if (e < NEDGE) atomicAdd(&h[dst[(size_t)r * NEDGE + e] >> 8], 1);
    }
    __syncthreads();
    for (int t = threadIdx.x; t < NBKT; t += 256)
        hist[((size_t)r * CH + c) * NBKT + t] = h[t];
}

__global__ __launch_bounds__(512) void scan_hist(int* __restrict__ hist,
                                                 int* __restrict__ tot) {
    const int b = blockIdx.x, r = blockIdx.y, t = threadIdx.x;
    __shared__ int s[512];
    const int v = (t < CH) ? hist[((size_t)r * CH + t) * NBKT + b] : 0;
    s[t] = v;
    __syncthreads();
    for (int off = 1; off < 512; off <<= 1) {
        const int u = (t >= off) ? s[t - off] : 0;
        __syncthreads();
        s[t] += u;
        __syncthreads();
    }
    if (t < CH) hist[((size_t)r * CH + t) * NBKT + b] = s[t] - v;   // exclusive
    if (t == 511) tot[r * NBKT + b] = s[511];
}

__global__ __launch_bounds__(256) void scan_tot(const int* __restrict__ tot,
                                                int* __restrict__ bktbase) {
    const int r = blockIdx.x, t = threadIdx.x;
    __shared__ int s[256];
    const int v = (t < NBKT) ? tot[r * NBKT + t] : 0;
    s[t] = v;
    __syncthreads();
    for (int off = 1; off < 256; off <<= 1) {
        const int u = (t >= off) ? s[t - off] : 0;
        __syncthreads();
        s[t] += u;
        __syncthreads();
    }
    if (t < NBKT) bktbase[r * NBKT + t] = s[t] - v;
}

__global__ __launch_bounds__(256) void scatter_bkt(const int* __restrict__ src,
                                                   const int* __restrict__ dst,
                                                   const int* __restrict__ hist,
                                                   const int* __restrict__ bktbase,
                                                   unsigned* __restrict__ pk) {
    const int c = blockIdx.x, r = blockIdx.y;
    __shared__ int off[NBKT];
    for (int t = threadIdx.x; t < NBKT; t += 256)
        off[t] = bktbase[r * NBKT + t] + hist[((size_t)r * CH + c) * NBKT + t];
    __syncthreads();
    #pragma unroll
    for (int u = 0; u < 8; ++u) {
        const int e = c * 2048 + u * 256 + threadIdx.x;
        if (e < NEDGE) {
            const int d = dst[(size_t)r * NEDGE + e];
            const int s = src[(size_t)r * NEDGE + e];
            const int p = atomicAdd(&off[d >> 8], 1);
            pk[(size_t)r * NEDGE + p] = ((unsigned)s << 8) | (unsigned)(d & 255);
        }
    }
}

__global__ __launch_bounds__(256) void build_csr(const unsigned* __restrict__ pk,
                                                 const int* __restrict__ tot,
                                                 const int* __restrict__ bktbase,
                                                 int* __restrict__ rptrg,
                                                 int* __restrict__ degg,
                                                 int* __restrict__ colg) {
    const int b = blockIdx.x, r = blockIdx.y, t = threadIdx.x;
    const int ebase = bktbase[r * NBKT + b];
    const int ecnt  = tot[r * NBKT + b];
    const unsigned* p = pk + (size_t)r * NEDGE + ebase;
    __shared__ int cnt[256], loc[256], run[256];
    cnt[t] = 0;
    __syncthreads();
    for (int i = t; i < ecnt; i += 256) atomicAdd(&cnt[p[i] & 255], 1);
    __syncthreads();
    const int v = cnt[t];
    loc[t] = v;
    __syncthreads();
    for (int off = 1; off < 256; off <<= 1) {
        const int u = (t >= off) ? loc[t - off] : 0;
        __syncthreads();
        loc[t] += u;
        __syncthreads();
    }
    const int excl = loc[t] - v;
    const int node = b * 256 + t;
    if (node < NNODES) {
        degg[r * NNODES + node]  = v;
        rptrg[r * NNODES + node] = ebase + excl;    // relation-local col index
    }
    run[t] = excl;
    __syncthreads();
    for (int i = t; i < ecnt; i += 256) {
        const unsigned w = p[i];
        const int q = atomicAdd(&run[w & 255], 1);
        colg[(size_t)r * NEDGE + ebase + q] = (int)(w >> 8);
    }
}

// ---------------------------------------------------------------------------
// 3. Pull aggregation, quarter-wave layout (unchanged from round 11):
//    16 lanes cover a 256B row (dwordx4 each); 4 edges in flight per wave;
//    unmasked full-16 blocks + masked tail; shfl pre-scaled byte offsets.
// ---------------------------------------------------------------------------
__global__ __launch_bounds__(256) void aggregate(const ushort* __restrict__ H,
                                                 const int* __restrict__ rptrg,
                                                 const int* __restrict__ degg,
                                                 const int* __restrict__ colg,
                                                 ushort* __restrict__ Xm) {
    const int wid = (blockIdx.x * 256 + threadIdx.x) >> 6;
    const int lane = threadIdx.x & 63;
    if (wid >= NREL * NNODES) return;
    const int r = wid / NNODES;
    const int n = wid - r * NNODES;
    const int e0 = rptrg[wid];
    const int dg = degg[wid];
    const int* cl = colg + (size_t)r * NEDGE + e0;
    const int es = lane >> 4;            // edge slot 0..3
    const int q  = lane & 15;            // col group: cols [8q..8q+8)
    const char* Hb = (const char*)H + q * 16;
    float a0 = 0.f, a1 = 0.f, a2 = 0.f, a3 = 0.f,
          a4 = 0.f, a5 = 0.f, a6 = 0.f, a7 = 0.f;
    for (int base = 0; base < dg; base += 64) {
        const int idx = base + lane;
        const int boff = (idx < dg) ? (cl[idx] << 8) : 0;    // row byte offset
        const int cnt = min(64, dg - base);
        int j = 0;
        for (; j + 16 <= cnt; j += 16) {                     // unmasked full blocks
            #pragma unroll
            for (int u = 0; u < 4; ++u) {
                const int ro = __shfl(boff, j + 4 * u + es);
                const uint4 w = *reinterpret_cast<const uint4*>(Hb + ro);
                a0 += __uint_as_float(w.x << 16);
                a1 += __uint_as_float(w.x & 0xffff0000u);
                a2 += __uint_as_float(w.y << 16);
                a3 += __uint_as_float(w.y & 0xffff0000u);
                a4 += __uint_as_float(w.z << 16);
                a5 += __uint_as_float(w.z & 0xffff0000u);
                a6 += __uint_as_float(w.w << 16);
                a7 += __uint_as_float(w.w & 0xffff0000u);
            }
        }
        if (j < cnt) {                                       // masked tail
            #pragma unroll
            for (int u = 0; u < 4; ++u) {
                const int eid = j + 4 * u + es;
                const int ro = __shfl(boff, eid);
                const float m = (eid < cnt) ? 1.f : 0.f;
                const uint4 w = *reinterpret_cast<const uint4*>(Hb + ro);
                a0 = fmaf(__uint_as_float(w.x << 16), m, a0);
                a1 = fmaf(__uint_as_float(w.x & 0xffff0000u), m, a1);
                a2 = fmaf(__uint_as_float(w.y << 16), m, a2);
                a3 = fmaf(__uint_as_float(w.y & 0xffff0000u), m, a3);
                a4 = fmaf(__uint_as_float(w.z << 16), m, a4);
                a5 = fmaf(__uint_as_float(w.z & 0xffff0000u), m, a5);
                a6 = fmaf(__uint_as_float(w.w << 16), m, a6);
                a7 = fmaf(__uint_as_float(w.w & 0xffff0000u), m, a7);
            }
        }
    }
    a0 += __shfl_xor(a0, 16); a1 += __shfl_xor(a1, 16);
    a2 += __shfl_xor(a2, 16); a3 += __shfl_xor(a3, 16);
    a4 += __shfl_xor(a4, 16); a5 += __shfl_xor(a5, 16);
    a6 += __shfl_xor(a6, 16); a7 += __shfl_xor(a7, 16);
    a0 += __shfl_xor(a0, 32); a1 += __shfl_xor(a1, 32);
    a2 += __shfl_xor(a2, 32); a3 += __shfl_xor(a3, 32);
    a4 += __shfl_xor(a4, 32); a5 += __shfl_xor(a5, 32);
    a6 += __shfl_xor(a6, 32); a7 += __shfl_xor(a7, 32);
    if (es == 0) {
        const float inv = 1.f / (float)max(dg, 1);
        ushortx8 o;
        o[0] = f2bf(a0 * inv); o[1] = f2bf(a1 * inv);
        o[2] = f2bf(a2 * inv); o[3] = f2bf(a3 * inv);
        o[4] = f2bf(a4 * inv); o[5] = f2bf(a5 * inv);
        o[6] = f2bf(a6 * inv); o[7] = f2bf(a7 * inv);
        *reinterpret_cast<ushortx8*>(Xm + (size_t)n * (NREL * DIM) + r * DIM + q * 8) = o;
    }
}

// ---------------------------------------------------------------------------
// 4. Split-bf16 MFMA GEMM, 64 rows/wave (4 row-tiles; halves per-row B-frag
//    L2 traffic vs 32 rows/wave):  Out = act([Hsrc|Xm] @ Wf + b)
//    Self cols (kt<4, fp32 src):  3 MFMAs (hi/lo split)
//    Mean cols (kt>=4, bf16 src): 2 MFMAs
//    No LDS, no barriers. In-place safe: wave reads only its own 64 rows
//    before storing; clamp-read races only affect never-stored tail rows.
// ---------------------------------------------------------------------------
template <bool RELU, bool WRITEBF>
__global__ __launch_bounds__(256) void gemm_mfma(const float* __restrict__ Hsrc,
                                                 const ushort* __restrict__ Xm,
                                                 const ushort* __restrict__ Whi,
                                                 const ushort* __restrict__ Wlo,
                                                 const float* __restrict__ bias,
                                                 float* __restrict__ Out,
                                                 ushort* __restrict__ OutBf) {
    const int wave = threadIdx.x >> 6;
    const int lane = threadIdx.x & 63;
    const int r16 = lane & 15;
    const int kg  = lane >> 4;                       // 0..3
    const int wbase = blockIdx.x * 256 + wave * 64;  // wave's 64 rows

    f32x4 acc[4][8];
    #pragma unroll
    for (int t = 0; t < 4; ++t)
        #pragma unroll
        for (int ct = 0; ct < 8; ++ct) acc[t][ct] = (f32x4)0.0f;

    int rowc[4];
    #pragma unroll
    for (int t = 0; t < 4; ++t) {
        int row = wbase + t * 16 + r16;
        rowc[t] = row < NNODES ? row : NNODES - 1;   // clamp; tail rows never stored
    }

    // ---- kt 0..3: self columns from fp32 Hsrc, hi/lo split (3 MFMAs)
    for (int kt = 0; kt < 4; ++kt) {
        const int kbase = kt * 32 + kg * 8;
        bf16x8 ahi[4], alo[4];
        #pragma unroll
        for (int t = 0; t < 4; ++t) {
            const float* sp = Hsrc + (size_t)rowc[t] * DIM + kbase;
            const float4 v0 = *reinterpret_cast<const float4*>(sp);
            const float4 v1 = *reinterpret_cast<const float4*>(sp + 4);
            const float xs[8] = {v0.x, v0.y, v0.z, v0.w, v1.x, v1.y, v1.z, v1.w};
            #pragma unroll
            for (int e = 0; e < 8; ++e) {
                const float x = xs[e];
                const ushort h = f2bf(x);
                ahi[t][e] = (short)h;
                alo[t][e] = (short)f2bf(x - bf2f(h));   // Sterbenz: subtraction exact
            }
        }
        const ushort* bp  = Whi + (size_t)(kt * 8) * 512 + kg * 128 + r16 * 8;
        const ushort* bpl = Wlo + (size_t)(kt * 8) * 512 + kg * 128 + r16 * 8;
        #pragma unroll
        for (int ct = 0; ct < 8; ++ct) {
            const bf16x8 bhi = *reinterpret_cast<const bf16x8*>(bp + ct * 512);
            const bf16x8 blo = *reinterpret_cast<const bf16x8*>(bpl + ct * 512);
            #pragma unroll
            for (int t = 0; t < 4; ++t) {
                acc[t][ct] = __builtin_amdgcn_mfma_f32_16x16x32_bf16(ahi[t], bhi, acc[t][ct], 0, 0, 0);
                acc[t][ct] = __builtin_amdgcn_mfma_f32_16x16x32_bf16(alo[t], bhi, acc[t][ct], 0, 0, 0);
                acc[t][ct] = __builtin_amdgcn_mfma_f32_16x16x32_bf16(ahi[t], blo, acc[t][ct], 0, 0, 0);
            }
        }
    }
    // ---- kt 4..15: mean columns from bf16 Xm, direct A-frag load (2 MFMAs)
    for (int kt = 4; kt < 16; ++kt) {
        const int kbase = kt * 32 + kg * 8 - DIM;    // offset within Xm row
        bf16x8 a[4];
        #pragma unroll
        for (int t = 0; t < 4; ++t)
            a[t] = *reinterpret_cast<const bf16x8*>(Xm + (size_t)rowc[t] * (NREL * DIM) + kbase);
        const ushort* bp  = Whi + (size_t)(kt * 8) * 512 + kg * 128 + r16 * 8;
        const ushort* bpl = Wlo + (size_t)(kt * 8) * 512 + kg * 128 + r16 * 8;
        #pragma unroll
        for (int ct = 0; ct < 8; ++ct) {
            const bf16x8 bhi = *reinterpret_cast<const bf16x8*>(bp + ct * 512);
            const bf16x8 blo = *reinterpret_cast<const bf16x8*>(bpl + ct * 512);
            #pragma unroll
            for (int t = 0; t < 4; ++t) {
                acc[t][ct] = __builtin_amdgcn_mfma_f32_16x16x32_bf16(a[t], bhi, acc[t][ct], 0, 0, 0);
                acc[t][ct] = __builtin_amdgcn_mfma_f32_16x16x32_bf16(a[t], blo, acc[t][ct], 0, 0, 0);
            }
        }
    }
    // epilogue: bias + optional ReLU + store (fp32, and bf16 copy if WRITEBF)
    float bias_r[8];
    #pragma unroll
    for (int ct = 0; ct < 8; ++ct) bias_r[ct] = bias[ct * 16 + r16];
    #pragma unroll
    for (int t = 0; t < 4; ++t) {
        #pragma unroll
        for (int q = 0; q < 4; ++q) {
            const int row = wbase + t * 16 + kg * 4 + q;
            if (row >= NNODES) continue;
            #pragma unroll
            for (int ct = 0; ct < 8; ++ct) {
                float v = acc[t][ct][q] + bias_r[ct];
                if (RELU) v = fmaxf(v, 0.f);
                Out[(size_t)row * DIM + ct * 16 + r16] = v;
                if (WRITEBF) OutBf[(size_t)row * DIM + ct * 16 + r16] = f2bf(v);
            }
        }
    }
}

// ---------------------------------------------------------------------------
extern "C" void kernel_launch(void* const* d_in, const int* in_sizes, int n_in,
                              void* d_out, int out_size, void* d_ws, size_t ws_size,
                              hipStream_t stream) {
    const float* feats  = (const float*)d_in[0];
    const int*   src    = (const int*)d_in[1];
    const int*   dst    = (const int*)d_in[2];
    const float* Wself  = (const float*)d_in[3];
    const float* bself  = (const float*)d_in[4];
    const float* Wneigh = (const float*)d_in[5];
    const float* Wm     = (const float*)d_in[6];
    const float* bmv    = (const float*)d_in[7];
    float* out = (float*)d_out;

    // workspace carve-up (4-byte words); H1 lives in d_out (in-place layer 1)
    float* ws      = (float*)d_ws;
    float* bias    = ws;                          // 256
    float* S       = bias + 256;                  // 2*128*128 = 32768
    int*   hist    = (int*)(S + 32768);           // 3*391*196 = 229908 -> pad 230016
    int*   tot     = hist + 230016;               // 588 -> pad 640
    int*   bktbase = tot + 640;                   // 640
    int*   rptrg   = bktbase + 640;               // 150000
    int*   degg    = rptrg + 150000;              // 150000
    unsigned* pk   = (unsigned*)(degg + 150000);  // 2400000
    int*   colg    = (int*)(pk + 2400000);        // 2400000
    ushort* Whi    = (ushort*)(colg + 2400000);   // 131072 u16 = 65536 words
    ushort* Wlo    = Whi + 131072;                // 65536 words
    ushort* Fbf    = Wlo + 131072;                // N*128 u16 = 3200000 words
    ushort* Xm     = Fbf + 6400000;               // N*384 u16 = 9600000 words
    float* H1      = out;
    // total ~= 73 MB

    sumS<<<dim3(DIM, 2), DIM, 0, stream>>>(Wm, S);
    prep_wsplit<<<dim3(513, 2), 128, 0, stream>>>(Wself, bself, Wneigh, Wm, bmv, S,
                                                  Whi, Wlo, bias);

    // CSR build (zero global atomics; built once, used by both layers)
    hist_bkt<<<dim3(CH, NREL), 256, 0, stream>>>(dst, hist);
    scan_hist<<<dim3(NBKT, NREL), 512, 0, stream>>>(hist, tot);
    scan_tot<<<NREL, 256, 0, stream>>>(tot, bktbase);
    scatter_bkt<<<dim3(CH, NREL), 256, 0, stream>>>(src, dst, hist, bktbase, pk);
    build_csr<<<dim3(NBKT, NREL), 256, 0, stream>>>(pk, tot, bktbase, rptrg, degg, colg);

    const int aggBlocks  = (NREL * NNODES) / 4;          // 4 waves/block, exact
    const int gemmBlocks = (NNODES + 255) / 256;         // 196 (64 rows/wave)
    const int cvtBlocks  = (NNODES * DIM) / 4 / 256;     // 6250, exact

    // layer 0  (GEMM also emits bf16 H1 -> Fbf, fusing layer-1's h2bf)
    h2bf<<<cvtBlocks, 256, 0, stream>>>(feats, Fbf);
    aggregate<<<aggBlocks, 256, 0, stream>>>(Fbf, rptrg, degg, colg, Xm);
    gemm_mfma<true, true><<<gemmBlocks, 256, 0, stream>>>(feats, Xm, Whi, Wlo, bias, H1, Fbf);

    // layer 1 (in place: Hsrc == Out == d_out)
    aggregate<<<aggBlocks, 256, 0, stream>>>(Fbf, rptrg, degg, colg, Xm);
    gemm_mfma<false, false><<<gemmBlocks, 256, 0, stream>>>(H1, Xm, Whi + 65536, Wlo + 65536,
                                                            bias + 128, out, Fbf);
}